// Round 1
// baseline (836.200 us; speedup 1.0000x reference)
//
#include <hip/hip_runtime.h>
#include <hip/hip_bf16.h>

#define N_TOK 2048
#define HIDDEN 1024
#define NHEAD 16
#define DHEAD 64

typedef __attribute__((ext_vector_type(8))) short bf16x8;
typedef __attribute__((ext_vector_type(4))) float f32x4;

__device__ inline unsigned short f2bf(float x) {
    __hip_bfloat16 h = __float2bfloat16(x);
    return *reinterpret_cast<unsigned short*>(&h);
}

__device__ inline f32x4 zero4() {
    f32x4 z;
    z[0] = 0.f; z[1] = 0.f; z[2] = 0.f; z[3] = 0.f;
    return z;
}

// ---------------- K0: f32 -> bf16 conversion (vectorized) ----------------
__global__ void cvt_kernel(const float* __restrict__ src, unsigned short* __restrict__ dst, int n4) {
    int i = blockIdx.x * blockDim.x + threadIdx.x;
    if (i < n4) {
        float4 v = reinterpret_cast<const float4*>(src)[i];
        ushort4 o;
        o.x = f2bf(v.x); o.y = f2bf(v.y); o.z = f2bf(v.z); o.w = f2bf(v.w);
        reinterpret_cast<ushort4*>(dst)[i] = o;
    }
}

// ---------------- K1: fused QKV GEMM  y[n,j] = sum_k xb[n,k]*wb[j,k] + bias ----------------
// 128x128 tile, BK=64, 4 waves (2x2), each wave 64x64 via 4x4 mfma_16x16x32_bf16 frags.
__launch_bounds__(256)
__global__ void gemm_qkv(const unsigned short* __restrict__ xb,
                         const unsigned short* __restrict__ wb,
                         const float* __restrict__ bq, const float* __restrict__ bk,
                         const float* __restrict__ bv,
                         unsigned short* __restrict__ qb, unsigned short* __restrict__ kb,
                         unsigned short* __restrict__ vb) {
    __shared__ unsigned short As[128 * 64];
    __shared__ unsigned short Bs[128 * 64];
    const int tid = threadIdx.x;
    const int lane = tid & 63;
    const int w = tid >> 6;
    const int wr = w >> 1, wc = w & 1;
    const int rb = blockIdx.y * 128;
    const int cb = blockIdx.x * 128;

    f32x4 acc[4][4];
    for (int i = 0; i < 4; i++)
        for (int j = 0; j < 4; j++) acc[i][j] = zero4();

    for (int kt = 0; kt < 16; ++kt) {
        __syncthreads();
#pragma unroll
        for (int i = 0; i < 4; i++) {
            int s = tid + 256 * i;
            int row = s >> 3, c = s & 7;
            uint4 va = *reinterpret_cast<const uint4*>(xb + (size_t)(rb + row) * HIDDEN + kt * 64 + c * 8);
            *reinterpret_cast<uint4*>(As + row * 64 + ((c ^ (row & 7)) << 3)) = va;
            uint4 vbv = *reinterpret_cast<const uint4*>(wb + (size_t)(cb + row) * HIDDEN + kt * 64 + c * 8);
            *reinterpret_cast<uint4*>(Bs + row * 64 + ((c ^ (row & 7)) << 3)) = vbv;
        }
        __syncthreads();
#pragma unroll
        for (int kk = 0; kk < 2; kk++) {
            bf16x8 a[4], b[4];
#pragma unroll
            for (int mi = 0; mi < 4; mi++) {
                int row = wr * 64 + mi * 16 + (lane & 15);
                a[mi] = *reinterpret_cast<const bf16x8*>(As + row * 64 + (((kk * 4 + (lane >> 4)) ^ (row & 7)) << 3));
            }
#pragma unroll
            for (int ni = 0; ni < 4; ni++) {
                int row = wc * 64 + ni * 16 + (lane & 15);
                b[ni] = *reinterpret_cast<const bf16x8*>(Bs + row * 64 + (((kk * 4 + (lane >> 4)) ^ (row & 7)) << 3));
            }
#pragma unroll
            for (int mi = 0; mi < 4; mi++)
#pragma unroll
                for (int ni = 0; ni < 4; ni++)
                    acc[mi][ni] = __builtin_amdgcn_mfma_f32_16x16x32_bf16(a[mi], b[ni], acc[mi][ni], 0, 0, 0);
        }
    }

    const int region = blockIdx.x >> 3;  // 0=q, 1=k, 2=v  (8 col-blocks of 128 per region)
    const float* bias = region == 0 ? bq : (region == 1 ? bk : bv);
    unsigned short* dst = region == 0 ? qb : (region == 1 ? kb : vb);
#pragma unroll
    for (int mi = 0; mi < 4; mi++) {
#pragma unroll
        for (int ni = 0; ni < 4; ni++) {
            int colg = cb + wc * 64 + ni * 16 + (lane & 15);
            int jj = colg & 1023;
            int hh = jj >> 6, d = jj & 63;
            float bval = bias[jj];
#pragma unroll
            for (int r = 0; r < 4; r++) {
                int n = rb + wr * 64 + mi * 16 + ((lane >> 4) << 2) + r;
                dst[((size_t)hh * N_TOK + n) * 64 + d] = f2bf(acc[mi][ni][r] + bval);
            }
        }
    }
}

// ---------------- K1b: transpose v [h][n][d] -> vbt [h][d][n] ----------------
__global__ void transpose_v(const unsigned short* __restrict__ vb, unsigned short* __restrict__ vbt) {
    int t = blockIdx.x * blockDim.x + threadIdx.x;  // 262144 threads
    int nc = t & 255, d = (t >> 8) & 63, h = t >> 14;
    int n0 = nc * 8;
    unsigned short tmp[8];
#pragma unroll
    for (int j = 0; j < 8; j++)
        tmp[j] = vb[((size_t)h * N_TOK + n0 + j) * 64 + d];
    *reinterpret_cast<uint4*>(vbt + ((size_t)h * 64 + d) * N_TOK + n0) = *reinterpret_cast<uint4*>(tmp);
}

// ---------------- K2: fused attention per (head, 64-row block) ----------------
// pass1: online-softmax stats; pass2: recompute S, write attn + new_history, PV via MFMA.
__launch_bounds__(256)
__global__ void attn_kernel(const unsigned short* __restrict__ qb,
                            const unsigned short* __restrict__ kb,
                            const unsigned short* __restrict__ vbt,
                            const float* __restrict__ hist,
                            const float* __restrict__ beta_p,
                            float* __restrict__ attn_out,
                            float* __restrict__ nh_out,
                            float* __restrict__ hv) {
    __shared__ unsigned short Qs[64 * 64];
    __shared__ unsigned short Ks[64 * 64];
    __shared__ unsigned short Vs[64 * 64];
    __shared__ unsigned short Ps[4][16 * 64];

    const int tid = threadIdx.x;
    const int lane = tid & 63;
    const int w = tid >> 6;
    const int h = blockIdx.y;
    const int n0 = blockIdx.x * 64;
    const float beta = beta_p[0];
    const float scale = 0.125f;  // 1/sqrt(64)

    {
        const unsigned short* src = qb + ((size_t)h * N_TOK + n0) * 64;
#pragma unroll
        for (int i = 0; i < 2; i++) {
            int s = tid + 256 * i;
            int row = s >> 3, c = s & 7;
            uint4 v = *reinterpret_cast<const uint4*>(src + row * 64 + c * 8);
            *reinterpret_cast<uint4*>(Qs + row * 64 + ((c ^ (row & 7)) << 3)) = v;
        }
    }
    __syncthreads();
    bf16x8 aq[2];
    {
        int row = w * 16 + (lane & 15);
        aq[0] = *reinterpret_cast<const bf16x8*>(Qs + row * 64 + ((((lane >> 4)) ^ (row & 7)) << 3));
        aq[1] = *reinterpret_cast<const bf16x8*>(Qs + row * 64 + (((4 + (lane >> 4)) ^ (row & 7)) << 3));
    }

    float m_r[4], l_r[4];
#pragma unroll
    for (int r = 0; r < 4; r++) { m_r[r] = -1e30f; l_r[r] = 0.0f; }

    const size_t hrow_base = ((size_t)h * N_TOK + n0) * N_TOK;

    // ---- pass 1: stats ----
    for (int t = 0; t < 32; t++) {
        __syncthreads();
        {
            const unsigned short* src = kb + ((size_t)h * N_TOK + t * 64) * 64;
#pragma unroll
            for (int i = 0; i < 2; i++) {
                int s = tid + 256 * i;
                int row = s >> 3, c = s & 7;
                uint4 v = *reinterpret_cast<const uint4*>(src + row * 64 + c * 8);
                *reinterpret_cast<uint4*>(Ks + row * 64 + ((c ^ (row & 7)) << 3)) = v;
            }
        }
        __syncthreads();
        f32x4 s_acc[4];
#pragma unroll
        for (int ni = 0; ni < 4; ni++) {
            s_acc[ni] = zero4();
#pragma unroll
            for (int kk = 0; kk < 2; kk++) {
                int row = ni * 16 + (lane & 15);
                bf16x8 b = *reinterpret_cast<const bf16x8*>(Ks + row * 64 + (((kk * 4 + (lane >> 4)) ^ (row & 7)) << 3));
                s_acc[ni] = __builtin_amdgcn_mfma_f32_16x16x32_bf16(aq[kk], b, s_acc[ni], 0, 0, 0);
            }
        }
        float sc[4][4];
#pragma unroll
        for (int ni = 0; ni < 4; ni++) {
            int col = t * 64 + ni * 16 + (lane & 15);
#pragma unroll
            for (int r = 0; r < 4; r++) {
                int rl = w * 16 + ((lane >> 4) << 2) + r;
                float hval = hist[hrow_base + (size_t)rl * N_TOK + col];
                sc[ni][r] = s_acc[ni][r] * scale + beta * hval;
            }
        }
#pragma unroll
        for (int r = 0; r < 4; r++) {
            float tm = fmaxf(fmaxf(sc[0][r], sc[1][r]), fmaxf(sc[2][r], sc[3][r]));
#pragma unroll
            for (int msk = 1; msk < 16; msk <<= 1) tm = fmaxf(tm, __shfl_xor(tm, msk));
            float mn = fmaxf(m_r[r], tm);
            float ps = 0.0f;
#pragma unroll
            for (int ni = 0; ni < 4; ni++) ps += __expf(sc[ni][r] - mn);
#pragma unroll
            for (int msk = 1; msk < 16; msk <<= 1) ps += __shfl_xor(ps, msk);
            l_r[r] = l_r[r] * __expf(m_r[r] - mn) + ps;
            m_r[r] = mn;
        }
    }
    float inv_l[4];
#pragma unroll
    for (int r = 0; r < 4; r++) inv_l[r] = 1.0f / l_r[r];

    f32x4 oacc[4];
#pragma unroll
    for (int ni = 0; ni < 4; ni++) oacc[ni] = zero4();

    // ---- pass 2: write attn/new_history, accumulate PV ----
    for (int t = 0; t < 32; t++) {
        __syncthreads();
        {
            const unsigned short* srck = kb + ((size_t)h * N_TOK + t * 64) * 64;
            const unsigned short* srcv = vbt + ((size_t)h * 64) * N_TOK + t * 64;
#pragma unroll
            for (int i = 0; i < 2; i++) {
                int s = tid + 256 * i;
                int row = s >> 3, c = s & 7;
                uint4 v = *reinterpret_cast<const uint4*>(srck + row * 64 + c * 8);
                *reinterpret_cast<uint4*>(Ks + row * 64 + ((c ^ (row & 7)) << 3)) = v;
                uint4 v2 = *reinterpret_cast<const uint4*>(srcv + (size_t)row * N_TOK + c * 8);
                *reinterpret_cast<uint4*>(Vs + row * 64 + ((c ^ (row & 7)) << 3)) = v2;
            }
        }
        __syncthreads();
        f32x4 s_acc[4];
#pragma unroll
        for (int ni = 0; ni < 4; ni++) {
            s_acc[ni] = zero4();
#pragma unroll
            for (int kk = 0; kk < 2; kk++) {
                int row = ni * 16 + (lane & 15);
                bf16x8 b = *reinterpret_cast<const bf16x8*>(Ks + row * 64 + (((kk * 4 + (lane >> 4)) ^ (row & 7)) << 3));
                s_acc[ni] = __builtin_amdgcn_mfma_f32_16x16x32_bf16(aq[kk], b, s_acc[ni], 0, 0, 0);
            }
        }
#pragma unroll
        for (int ni = 0; ni < 4; ni++) {
            int col = t * 64 + ni * 16 + (lane & 15);
#pragma unroll
            for (int r = 0; r < 4; r++) {
                int rl = w * 16 + ((lane >> 4) << 2) + r;
                size_t gidx = hrow_base + (size_t)rl * N_TOK + col;
                float hval = hist[gidx];
                float s = s_acc[ni][r] * scale + beta * hval;
                float a = __expf(s - m_r[r]) * inv_l[r];
                attn_out[gidx] = a;
                nh_out[gidx] = a + hval;
                int prow = ((lane >> 4) << 2) + r;
                int pcol = ni * 16 + (lane & 15);
                Ps[w][prow * 64 + (pcol ^ ((prow & 7) << 3))] = f2bf(a);
            }
        }
        __syncthreads();  // make Ps visible to whole wave/block before PV reads
#pragma unroll
        for (int kk = 0; kk < 2; kk++) {
            int prow = lane & 15;
            bf16x8 pa = *reinterpret_cast<const bf16x8*>(Ps[w] + prow * 64 + (((kk * 4 + (lane >> 4)) ^ (prow & 7)) << 3));
#pragma unroll
            for (int ni = 0; ni < 4; ni++) {
                int vrow = ni * 16 + (lane & 15);  // d index
                bf16x8 vfr = *reinterpret_cast<const bf16x8*>(Vs + vrow * 64 + (((kk * 4 + (lane >> 4)) ^ (vrow & 7)) << 3));
                oacc[ni] = __builtin_amdgcn_mfma_f32_16x16x32_bf16(pa, vfr, oacc[ni], 0, 0, 0);
            }
        }
    }
#pragma unroll
    for (int ni = 0; ni < 4; ni++) {
#pragma unroll
        for (int r = 0; r < 4; r++) {
            int rl = w * 16 + ((lane >> 4) << 2) + r;
            int d = ni * 16 + (lane & 15);
            hv[((size_t)h * N_TOK + n0 + rl) * 64 + d] = oacc[ni][r];
        }
    }
}

// ---------------- K3: out[n,dd] = sum_j hv_flat[n,j] * Wo[dd,j] + bo[dd] ----------------
__launch_bounds__(256)
__global__ void out_proj(const float* __restrict__ hv, const float* __restrict__ Wo,
                         const float* __restrict__ bo, float* __restrict__ out) {
    __shared__ float wos[64][129];
    const int tid = threadIdx.x;
    const int dd = tid & 63;
    const int w = tid >> 6;
    const int n0 = blockIdx.x * 16;
    float acc[4] = {0.f, 0.f, 0.f, 0.f};
    for (int kc = 0; kc < 1024; kc += 128) {
        __syncthreads();
#pragma unroll
        for (int i = 0; i < 32; i++) {
            int e = tid + 256 * i;
            int r = e >> 7, j = e & 127;
            wos[r][j] = Wo[(size_t)r * 1024 + kc + j];
        }
        __syncthreads();
#pragma unroll 4
        for (int k = 0; k < 128; k++) {
            float wv = wos[dd][k];
            int jg = kc + k;
            const float* hb = hv + ((size_t)(jg >> 6) * N_TOK) * 64 + (jg & 63);
#pragma unroll
            for (int q = 0; q < 4; q++) {
                acc[q] += hb[(size_t)(n0 + w + 4 * q) * 64] * wv;  // uniform address -> scalar load
            }
        }
    }
#pragma unroll
    for (int q = 0; q < 4; q++)
        out[(size_t)(n0 + w + 4 * q) * 64 + dd] = acc[q] + bo[dd];
}

extern "C" void kernel_launch(void* const* d_in, const int* in_sizes, int n_in,
                              void* d_out, int out_size, void* d_ws, size_t ws_size,
                              hipStream_t stream) {
    const float* x    = (const float*)d_in[0];
    const float* hist = (const float*)d_in[1];
    const float* Wq_w = (const float*)d_in[2];
    const float* Wq_b = (const float*)d_in[3];
    const float* Wk_w = (const float*)d_in[4];
    const float* Wk_b = (const float*)d_in[5];
    const float* Wv_w = (const float*)d_in[6];
    const float* Wv_b = (const float*)d_in[7];
    const float* Wo_w = (const float*)d_in[8];
    const float* Wo_b = (const float*)d_in[9];
    const float* beta = (const float*)d_in[10];

    float* out = (float*)d_out;
    float* attn_out = out + 131072;
    float* nh_out = attn_out + (size_t)NHEAD * N_TOK * N_TOK;

    unsigned short* xb  = (unsigned short*)d_ws;                 // 2M elems
    unsigned short* wb  = xb + (size_t)N_TOK * HIDDEN;           // 3M elems
    unsigned short* qb  = wb + (size_t)3 * HIDDEN * HIDDEN;      // 2M
    unsigned short* kb  = qb + (size_t)N_TOK * HIDDEN;
    unsigned short* vb  = kb + (size_t)N_TOK * HIDDEN;
    unsigned short* vbt = vb + (size_t)N_TOK * HIDDEN;
    float* hvb = (float*)(vbt + (size_t)N_TOK * HIDDEN);         // 2M f32

    cvt_kernel<<<2048, 256, 0, stream>>>(x, xb, N_TOK * HIDDEN / 4);
    cvt_kernel<<<1024, 256, 0, stream>>>(Wq_w, wb, HIDDEN * HIDDEN / 4);
    cvt_kernel<<<1024, 256, 0, stream>>>(Wk_w, wb + HIDDEN * HIDDEN, HIDDEN * HIDDEN / 4);
    cvt_kernel<<<1024, 256, 0, stream>>>(Wv_w, wb + 2 * HIDDEN * HIDDEN, HIDDEN * HIDDEN / 4);
    gemm_qkv<<<dim3(24, 16), 256, 0, stream>>>(xb, wb, Wq_b, Wk_b, Wv_b, qb, kb, vb);
    transpose_v<<<1024, 256, 0, stream>>>(vb, vbt);
    attn_kernel<<<dim3(32, 16), 256, 0, stream>>>(qb, kb, vbt, hist, beta, attn_out, nh_out, hvb);
    out_proj<<<128, 256, 0, stream>>>(hvb, Wo_w, Wo_b, out);
}

// Round 2
// 751.077 us; speedup vs baseline: 1.1133x; 1.1133x over previous
//
#include <hip/hip_runtime.h>
#include <hip/hip_bf16.h>

#define N_TOK 2048
#define HIDDEN 1024
#define NHEAD 16
#define DHEAD 64

typedef __attribute__((ext_vector_type(8))) short bf16x8;
typedef __attribute__((ext_vector_type(4))) float f32x4;

__device__ inline unsigned short f2bf(float x) {
    __hip_bfloat16 h = __float2bfloat16(x);
    return *reinterpret_cast<unsigned short*>(&h);
}

__device__ inline f32x4 zero4() {
    f32x4 z;
    z[0] = 0.f; z[1] = 0.f; z[2] = 0.f; z[3] = 0.f;
    return z;
}

// ---------------- K0: f32 -> bf16 conversion (vectorized) ----------------
__global__ void cvt_kernel(const float* __restrict__ src, unsigned short* __restrict__ dst, int n4) {
    int i = blockIdx.x * blockDim.x + threadIdx.x;
    if (i < n4) {
        float4 v = reinterpret_cast<const float4*>(src)[i];
        ushort4 o;
        o.x = f2bf(v.x); o.y = f2bf(v.y); o.z = f2bf(v.z); o.w = f2bf(v.w);
        reinterpret_cast<ushort4*>(dst)[i] = o;
    }
}

// ---------------- K1: fused QKV GEMM ----------------
__launch_bounds__(256)
__global__ void gemm_qkv(const unsigned short* __restrict__ xb,
                         const unsigned short* __restrict__ wb,
                         const float* __restrict__ bq, const float* __restrict__ bk,
                         const float* __restrict__ bv,
                         unsigned short* __restrict__ qb, unsigned short* __restrict__ kb,
                         unsigned short* __restrict__ vb) {
    __shared__ unsigned short As[128 * 64];
    __shared__ unsigned short Bs[128 * 64];
    const int tid = threadIdx.x;
    const int lane = tid & 63;
    const int w = tid >> 6;
    const int wr = w >> 1, wc = w & 1;
    const int rb = blockIdx.y * 128;
    const int cb = blockIdx.x * 128;

    f32x4 acc[4][4];
    for (int i = 0; i < 4; i++)
        for (int j = 0; j < 4; j++) acc[i][j] = zero4();

    for (int kt = 0; kt < 16; ++kt) {
        __syncthreads();
#pragma unroll
        for (int i = 0; i < 4; i++) {
            int s = tid + 256 * i;
            int row = s >> 3, c = s & 7;
            uint4 va = *reinterpret_cast<const uint4*>(xb + (size_t)(rb + row) * HIDDEN + kt * 64 + c * 8);
            *reinterpret_cast<uint4*>(As + row * 64 + ((c ^ (row & 7)) << 3)) = va;
            uint4 vbv = *reinterpret_cast<const uint4*>(wb + (size_t)(cb + row) * HIDDEN + kt * 64 + c * 8);
            *reinterpret_cast<uint4*>(Bs + row * 64 + ((c ^ (row & 7)) << 3)) = vbv;
        }
        __syncthreads();
#pragma unroll
        for (int kk = 0; kk < 2; kk++) {
            bf16x8 a[4], b[4];
#pragma unroll
            for (int mi = 0; mi < 4; mi++) {
                int row = wr * 64 + mi * 16 + (lane & 15);
                a[mi] = *reinterpret_cast<const bf16x8*>(As + row * 64 + (((kk * 4 + (lane >> 4)) ^ (row & 7)) << 3));
            }
#pragma unroll
            for (int ni = 0; ni < 4; ni++) {
                int row = wc * 64 + ni * 16 + (lane & 15);
                b[ni] = *reinterpret_cast<const bf16x8*>(Bs + row * 64 + (((kk * 4 + (lane >> 4)) ^ (row & 7)) << 3));
            }
#pragma unroll
            for (int mi = 0; mi < 4; mi++)
#pragma unroll
                for (int ni = 0; ni < 4; ni++)
                    acc[mi][ni] = __builtin_amdgcn_mfma_f32_16x16x32_bf16(a[mi], b[ni], acc[mi][ni], 0, 0, 0);
        }
    }

    const int region = blockIdx.x >> 3;  // 0=q, 1=k, 2=v
    const float* bias = region == 0 ? bq : (region == 1 ? bk : bv);
    unsigned short* dst = region == 0 ? qb : (region == 1 ? kb : vb);
#pragma unroll
    for (int mi = 0; mi < 4; mi++) {
#pragma unroll
        for (int ni = 0; ni < 4; ni++) {
            int colg = cb + wc * 64 + ni * 16 + (lane & 15);
            int jj = colg & 1023;
            int hh = jj >> 6, d = jj & 63;
            float bval = bias[jj];
#pragma unroll
            for (int r = 0; r < 4; r++) {
                int n = rb + wr * 64 + mi * 16 + ((lane >> 4) << 2) + r;
                dst[((size_t)hh * N_TOK + n) * 64 + d] = f2bf(acc[mi][ni][r] + bval);
            }
        }
    }
}

// ---------------- K1b: transpose v [h][n][d] -> vbt [h][d][n] ----------------
__global__ void transpose_v(const unsigned short* __restrict__ vb, unsigned short* __restrict__ vbt) {
    int t = blockIdx.x * blockDim.x + threadIdx.x;
    int nc = t & 255, d = (t >> 8) & 63, h = t >> 14;
    int n0 = nc * 8;
    unsigned short tmp[8];
#pragma unroll
    for (int j = 0; j < 8; j++)
        tmp[j] = vb[((size_t)h * N_TOK + n0 + j) * 64 + d];
    *reinterpret_cast<uint4*>(vbt + ((size_t)h * 64 + d) * N_TOK + n0) = *reinterpret_cast<uint4*>(tmp);
}

// ---------------- K2a: per-chunk online-softmax stats ----------------
// grid (chunk=4, rowblock=32, head=16); each block: 64 rows x 512 cols.
__launch_bounds__(256)
__global__ void attn_stats(const unsigned short* __restrict__ qb,
                           const unsigned short* __restrict__ kb,
                           const float* __restrict__ hist,
                           const float* __restrict__ beta_p,
                           float* __restrict__ m_part,
                           float* __restrict__ l_part) {
    __shared__ unsigned short Qs[64 * 64];
    __shared__ unsigned short Ks[64 * 64];
    const int tid = threadIdx.x;
    const int lane = tid & 63;
    const int w = tid >> 6;
    const int chunk = blockIdx.x;
    const int rb = blockIdx.y;
    const int h = blockIdx.z;
    const int n0 = rb * 64;
    const float beta = beta_p[0];
    const float scale = 0.125f;

    {
        const unsigned short* src = qb + ((size_t)h * N_TOK + n0) * 64;
#pragma unroll
        for (int i = 0; i < 2; i++) {
            int s = tid + 256 * i;
            int row = s >> 3, c = s & 7;
            uint4 v = *reinterpret_cast<const uint4*>(src + row * 64 + c * 8);
            *reinterpret_cast<uint4*>(Qs + row * 64 + ((c ^ (row & 7)) << 3)) = v;
        }
    }
    __syncthreads();
    bf16x8 aq[2];
    {
        int row = w * 16 + (lane & 15);
        aq[0] = *reinterpret_cast<const bf16x8*>(Qs + row * 64 + ((((lane >> 4)) ^ (row & 7)) << 3));
        aq[1] = *reinterpret_cast<const bf16x8*>(Qs + row * 64 + (((4 + (lane >> 4)) ^ (row & 7)) << 3));
    }

    float m_r[4], l_r[4];
#pragma unroll
    for (int r = 0; r < 4; r++) { m_r[r] = -1e30f; l_r[r] = 0.0f; }

    const size_t hrow_base = ((size_t)h * N_TOK + n0) * N_TOK;

    for (int ct = 0; ct < 8; ct++) {
        const int c0 = chunk * 512 + ct * 64;
        __syncthreads();
        {
            const unsigned short* src = kb + ((size_t)h * N_TOK + c0) * 64;
#pragma unroll
            for (int i = 0; i < 2; i++) {
                int s = tid + 256 * i;
                int row = s >> 3, c = s & 7;
                uint4 v = *reinterpret_cast<const uint4*>(src + row * 64 + c * 8);
                *reinterpret_cast<uint4*>(Ks + row * 64 + ((c ^ (row & 7)) << 3)) = v;
            }
        }
        __syncthreads();
        f32x4 s_acc[4];
#pragma unroll
        for (int ni = 0; ni < 4; ni++) {
            s_acc[ni] = zero4();
#pragma unroll
            for (int kk = 0; kk < 2; kk++) {
                int row = ni * 16 + (lane & 15);
                bf16x8 b = *reinterpret_cast<const bf16x8*>(Ks + row * 64 + (((kk * 4 + (lane >> 4)) ^ (row & 7)) << 3));
                s_acc[ni] = __builtin_amdgcn_mfma_f32_16x16x32_bf16(aq[kk], b, s_acc[ni], 0, 0, 0);
            }
        }
        float sc[4][4];
#pragma unroll
        for (int ni = 0; ni < 4; ni++) {
            int col = c0 + ni * 16 + (lane & 15);
#pragma unroll
            for (int r = 0; r < 4; r++) {
                int rl = w * 16 + ((lane >> 4) << 2) + r;
                float hval = hist[hrow_base + (size_t)rl * N_TOK + col];
                sc[ni][r] = s_acc[ni][r] * scale + beta * hval;
            }
        }
#pragma unroll
        for (int r = 0; r < 4; r++) {
            float tm = fmaxf(fmaxf(sc[0][r], sc[1][r]), fmaxf(sc[2][r], sc[3][r]));
#pragma unroll
            for (int msk = 1; msk < 16; msk <<= 1) tm = fmaxf(tm, __shfl_xor(tm, msk));
            float mn = fmaxf(m_r[r], tm);
            float ps = 0.0f;
#pragma unroll
            for (int ni = 0; ni < 4; ni++) ps += __expf(sc[ni][r] - mn);
#pragma unroll
            for (int msk = 1; msk < 16; msk <<= 1) ps += __shfl_xor(ps, msk);
            l_r[r] = l_r[r] * __expf(m_r[r] - mn) + ps;
            m_r[r] = mn;
        }
    }

    // partials layout: [h][rb][chunk][64 rows]
    const int base = (((h * 32 + rb) * 4 + chunk) * 64);
    if ((lane & 15) == 0) {
#pragma unroll
        for (int r = 0; r < 4; r++) {
            int rl = w * 16 + ((lane >> 4) << 2) + r;
            m_part[base + rl] = m_r[r];
            l_part[base + rl] = l_r[r];
        }
    }
}

// ---------------- K2b: finalize — merge stats, write attn/nh, PV partials ----------------
// grid (chunk=4, rowblock=32, head=16); LDS 24KB (P aliases dead Q buffer).
__launch_bounds__(256)
__global__ void attn_finalize(const unsigned short* __restrict__ qb,
                              const unsigned short* __restrict__ kb,
                              const unsigned short* __restrict__ vbt,
                              const float* __restrict__ hist,
                              const float* __restrict__ beta_p,
                              const float* __restrict__ m_part,
                              const float* __restrict__ l_part,
                              float* __restrict__ attn_out,
                              float* __restrict__ nh_out,
                              float* __restrict__ opart) {
    __shared__ unsigned short Qs[64 * 64];  // reused as P after q-frag extraction
    __shared__ unsigned short Ks[64 * 64];
    __shared__ unsigned short Vs[64 * 64];
    const int tid = threadIdx.x;
    const int lane = tid & 63;
    const int w = tid >> 6;
    const int chunk = blockIdx.x;
    const int rb = blockIdx.y;
    const int h = blockIdx.z;
    const int n0 = rb * 64;
    const float beta = beta_p[0];
    const float scale = 0.125f;

    {
        const unsigned short* src = qb + ((size_t)h * N_TOK + n0) * 64;
#pragma unroll
        for (int i = 0; i < 2; i++) {
            int s = tid + 256 * i;
            int row = s >> 3, c = s & 7;
            uint4 v = *reinterpret_cast<const uint4*>(src + row * 64 + c * 8);
            *reinterpret_cast<uint4*>(Qs + row * 64 + ((c ^ (row & 7)) << 3)) = v;
        }
    }
    __syncthreads();
    bf16x8 aq[2];
    {
        int row = w * 16 + (lane & 15);
        aq[0] = *reinterpret_cast<const bf16x8*>(Qs + row * 64 + ((((lane >> 4)) ^ (row & 7)) << 3));
        aq[1] = *reinterpret_cast<const bf16x8*>(Qs + row * 64 + (((4 + (lane >> 4)) ^ (row & 7)) << 3));
    }

    // merge per-chunk stats -> global m, inv_l for this row block
    float m_r[4], inv_l[4];
    {
        const int pbase = (h * 32 + rb) * 4 * 64;
#pragma unroll
        for (int r = 0; r < 4; r++) {
            int rl = w * 16 + ((lane >> 4) << 2) + r;
            float m0 = m_part[pbase + 0 * 64 + rl];
            float m1 = m_part[pbase + 1 * 64 + rl];
            float m2 = m_part[pbase + 2 * 64 + rl];
            float m3 = m_part[pbase + 3 * 64 + rl];
            float mm = fmaxf(fmaxf(m0, m1), fmaxf(m2, m3));
            float ll = l_part[pbase + 0 * 64 + rl] * __expf(m0 - mm)
                     + l_part[pbase + 1 * 64 + rl] * __expf(m1 - mm)
                     + l_part[pbase + 2 * 64 + rl] * __expf(m2 - mm)
                     + l_part[pbase + 3 * 64 + rl] * __expf(m3 - mm);
            m_r[r] = mm;
            inv_l[r] = 1.0f / ll;
        }
    }

    f32x4 oacc[4];
#pragma unroll
    for (int ni = 0; ni < 4; ni++) oacc[ni] = zero4();

    unsigned short* Ps = Qs + w * (16 * 64);  // per-wave P region (aliases Q rows w*16..w*16+15)
    const size_t hrow_base = ((size_t)h * N_TOK + n0) * N_TOK;

    for (int ct = 0; ct < 8; ct++) {
        const int c0 = chunk * 512 + ct * 64;
        __syncthreads();
        {
            const unsigned short* srck = kb + ((size_t)h * N_TOK + c0) * 64;
            const unsigned short* srcv = vbt + ((size_t)h * 64) * N_TOK + c0;
#pragma unroll
            for (int i = 0; i < 2; i++) {
                int s = tid + 256 * i;
                int row = s >> 3, c = s & 7;
                uint4 v = *reinterpret_cast<const uint4*>(srck + row * 64 + c * 8);
                *reinterpret_cast<uint4*>(Ks + row * 64 + ((c ^ (row & 7)) << 3)) = v;
                uint4 v2 = *reinterpret_cast<const uint4*>(srcv + (size_t)row * N_TOK + c * 8);
                *reinterpret_cast<uint4*>(Vs + row * 64 + ((c ^ (row & 7)) << 3)) = v2;
            }
        }
        __syncthreads();
        f32x4 s_acc[4];
#pragma unroll
        for (int ni = 0; ni < 4; ni++) {
            s_acc[ni] = zero4();
#pragma unroll
            for (int kk = 0; kk < 2; kk++) {
                int row = ni * 16 + (lane & 15);
                bf16x8 b = *reinterpret_cast<const bf16x8*>(Ks + row * 64 + (((kk * 4 + (lane >> 4)) ^ (row & 7)) << 3));
                s_acc[ni] = __builtin_amdgcn_mfma_f32_16x16x32_bf16(aq[kk], b, s_acc[ni], 0, 0, 0);
            }
        }
#pragma unroll
        for (int ni = 0; ni < 4; ni++) {
            int col = c0 + ni * 16 + (lane & 15);
#pragma unroll
            for (int r = 0; r < 4; r++) {
                int rl = w * 16 + ((lane >> 4) << 2) + r;
                size_t gidx = hrow_base + (size_t)rl * N_TOK + col;
                float hval = hist[gidx];
                float s = s_acc[ni][r] * scale + beta * hval;
                float a = __expf(s - m_r[r]) * inv_l[r];
                attn_out[gidx] = a;
                nh_out[gidx] = a + hval;
                int prow = ((lane >> 4) << 2) + r;
                int pcol = ni * 16 + (lane & 15);
                Ps[prow * 64 + (pcol ^ ((prow & 7) << 3))] = f2bf(a);
            }
        }
        // P is per-wave; compiler-inserted lgkmcnt orders the ds_write->ds_read.
#pragma unroll
        for (int kk = 0; kk < 2; kk++) {
            int prow = lane & 15;
            bf16x8 pa = *reinterpret_cast<const bf16x8*>(Ps + prow * 64 + (((kk * 4 + (lane >> 4)) ^ (prow & 7)) << 3));
#pragma unroll
            for (int ni = 0; ni < 4; ni++) {
                int vrow = ni * 16 + (lane & 15);  // d index
                bf16x8 vfr = *reinterpret_cast<const bf16x8*>(Vs + vrow * 64 + (((kk * 4 + (lane >> 4)) ^ (vrow & 7)) << 3));
                oacc[ni] = __builtin_amdgcn_mfma_f32_16x16x32_bf16(pa, vfr, oacc[ni], 0, 0, 0);
            }
        }
    }
    // PV partial for this chunk: opart[chunk][h][n][d]
#pragma unroll
    for (int ni = 0; ni < 4; ni++) {
#pragma unroll
        for (int r = 0; r < 4; r++) {
            int rl = w * 16 + ((lane >> 4) << 2) + r;
            int d = ni * 16 + (lane & 15);
            opart[((size_t)(chunk * NHEAD + h) * N_TOK + n0 + rl) * 64 + d] = oacc[ni][r];
        }
    }
}

// ---------------- K2c: reduce PV partials ----------------
__global__ void reduce_hv(const float4* __restrict__ op, float4* __restrict__ hv) {
    size_t i = (size_t)blockIdx.x * blockDim.x + threadIdx.x;  // 524288 float4s
    const size_t C = (size_t)NHEAD * N_TOK * DHEAD / 4;
    float4 a = op[i], b = op[i + C], c = op[i + 2 * C], d = op[i + 3 * C];
    float4 r;
    r.x = a.x + b.x + c.x + d.x;
    r.y = a.y + b.y + c.y + d.y;
    r.z = a.z + b.z + c.z + d.z;
    r.w = a.w + b.w + c.w + d.w;
    hv[i] = r;
}

// ---------------- K3: output projection ----------------
__launch_bounds__(256)
__global__ void out_proj(const float* __restrict__ hv, const float* __restrict__ Wo,
                         const float* __restrict__ bo, float* __restrict__ out) {
    __shared__ float wos[64][129];
    const int tid = threadIdx.x;
    const int dd = tid & 63;
    const int w = tid >> 6;
    const int n0 = blockIdx.x * 16;
    float acc[4] = {0.f, 0.f, 0.f, 0.f};
    for (int kc = 0; kc < 1024; kc += 128) {
        __syncthreads();
#pragma unroll
        for (int i = 0; i < 32; i++) {
            int e = tid + 256 * i;
            int r = e >> 7, j = e & 127;
            wos[r][j] = Wo[(size_t)r * 1024 + kc + j];
        }
        __syncthreads();
#pragma unroll 4
        for (int k = 0; k < 128; k++) {
            float wv = wos[dd][k];
            int jg = kc + k;
            const float* hb = hv + ((size_t)(jg >> 6) * N_TOK) * 64 + (jg & 63);
#pragma unroll
            for (int q = 0; q < 4; q++) {
                acc[q] += hb[(size_t)(n0 + w + 4 * q) * 64] * wv;
            }
        }
    }
#pragma unroll
    for (int q = 0; q < 4; q++)
        out[(size_t)(n0 + w + 4 * q) * 64 + dd] = acc[q] + bo[dd];
}

extern "C" void kernel_launch(void* const* d_in, const int* in_sizes, int n_in,
                              void* d_out, int out_size, void* d_ws, size_t ws_size,
                              hipStream_t stream) {
    const float* x    = (const float*)d_in[0];
    const float* hist = (const float*)d_in[1];
    const float* Wq_w = (const float*)d_in[2];
    const float* Wq_b = (const float*)d_in[3];
    const float* Wk_w = (const float*)d_in[4];
    const float* Wk_b = (const float*)d_in[5];
    const float* Wv_w = (const float*)d_in[6];
    const float* Wv_b = (const float*)d_in[7];
    const float* Wo_w = (const float*)d_in[8];
    const float* Wo_b = (const float*)d_in[9];
    const float* beta = (const float*)d_in[10];

    float* out = (float*)d_out;
    float* attn_out = out + 131072;
    float* nh_out = attn_out + (size_t)NHEAD * N_TOK * N_TOK;

    unsigned short* xb  = (unsigned short*)d_ws;                 // 2M shorts
    unsigned short* wb  = xb + (size_t)N_TOK * HIDDEN;           // 3M shorts
    unsigned short* qb  = wb + (size_t)3 * HIDDEN * HIDDEN;      // 2M
    unsigned short* kb  = qb + (size_t)N_TOK * HIDDEN;
    unsigned short* vb  = kb + (size_t)N_TOK * HIDDEN;
    unsigned short* vbt = vb + (size_t)N_TOK * HIDDEN;
    float* hvb    = (float*)(vbt + (size_t)N_TOK * HIDDEN);      // 2M f32
    float* m_part = hvb + (size_t)N_TOK * HIDDEN;                // 128K f32
    float* l_part = m_part + 16 * 32 * 4 * 64;                   // 128K f32
    float* opart  = l_part + 16 * 32 * 4 * 64;                   // 8M f32 (32MB)

    cvt_kernel<<<2048, 256, 0, stream>>>(x, xb, N_TOK * HIDDEN / 4);
    cvt_kernel<<<1024, 256, 0, stream>>>(Wq_w, wb, HIDDEN * HIDDEN / 4);
    cvt_kernel<<<1024, 256, 0, stream>>>(Wk_w, wb + HIDDEN * HIDDEN, HIDDEN * HIDDEN / 4);
    cvt_kernel<<<1024, 256, 0, stream>>>(Wv_w, wb + 2 * HIDDEN * HIDDEN, HIDDEN * HIDDEN / 4);
    gemm_qkv<<<dim3(24, 16), 256, 0, stream>>>(xb, wb, Wq_b, Wk_b, Wv_b, qb, kb, vb);
    transpose_v<<<1024, 256, 0, stream>>>(vb, vbt);
    attn_stats<<<dim3(4, 32, 16), 256, 0, stream>>>(qb, kb, hist, beta, m_part, l_part);
    attn_finalize<<<dim3(4, 32, 16), 256, 0, stream>>>(qb, kb, vbt, hist, beta, m_part, l_part,
                                                       attn_out, nh_out, opart);
    reduce_hv<<<2048, 256, 0, stream>>>((const float4*)opart, (float4*)hvb);
    out_proj<<<128, 256, 0, stream>>>(hvb, Wo_w, Wo_b, out);
}

// Round 3
// 467.704 us; speedup vs baseline: 1.7879x; 1.6059x over previous
//
#include <hip/hip_runtime.h>
#include <hip/hip_bf16.h>

#define N_TOK 2048
#define HIDDEN 1024
#define NHEAD 16
#define DHEAD 64

typedef __attribute__((ext_vector_type(8))) short bf16x8;
typedef __attribute__((ext_vector_type(4))) float f32x4;

__device__ inline unsigned short f2bf(float x) {
    __hip_bfloat16 h = __float2bfloat16(x);
    return *reinterpret_cast<unsigned short*>(&h);
}

__device__ inline f32x4 zero4() {
    f32x4 z;
    z[0] = 0.f; z[1] = 0.f; z[2] = 0.f; z[3] = 0.f;
    return z;
}

// ---------------- K0: f32 -> bf16 conversion (vectorized) ----------------
__global__ void cvt_kernel(const float* __restrict__ src, unsigned short* __restrict__ dst, int n4) {
    int i = blockIdx.x * blockDim.x + threadIdx.x;
    if (i < n4) {
        float4 v = reinterpret_cast<const float4*>(src)[i];
        ushort4 o;
        o.x = f2bf(v.x); o.y = f2bf(v.y); o.z = f2bf(v.z); o.w = f2bf(v.w);
        reinterpret_cast<ushort4*>(dst)[i] = o;
    }
}

// ---------------- K1: fused QKV GEMM ----------------
__launch_bounds__(256)
__global__ void gemm_qkv(const unsigned short* __restrict__ xb,
                         const unsigned short* __restrict__ wb,
                         const float* __restrict__ bq, const float* __restrict__ bk,
                         const float* __restrict__ bv,
                         unsigned short* __restrict__ qb, unsigned short* __restrict__ kb,
                         unsigned short* __restrict__ vb) {
    __shared__ unsigned short As[128 * 64];
    __shared__ unsigned short Bs[128 * 64];
    const int tid = threadIdx.x;
    const int lane = tid & 63;
    const int w = tid >> 6;
    const int wr = w >> 1, wc = w & 1;
    const int rb = blockIdx.y * 128;
    const int cb = blockIdx.x * 128;

    f32x4 acc[4][4];
    for (int i = 0; i < 4; i++)
        for (int j = 0; j < 4; j++) acc[i][j] = zero4();

    for (int kt = 0; kt < 16; ++kt) {
        __syncthreads();
#pragma unroll
        for (int i = 0; i < 4; i++) {
            int s = tid + 256 * i;
            int row = s >> 3, c = s & 7;
            uint4 va = *reinterpret_cast<const uint4*>(xb + (size_t)(rb + row) * HIDDEN + kt * 64 + c * 8);
            *reinterpret_cast<uint4*>(As + row * 64 + ((c ^ (row & 7)) << 3)) = va;
            uint4 vbv = *reinterpret_cast<const uint4*>(wb + (size_t)(cb + row) * HIDDEN + kt * 64 + c * 8);
            *reinterpret_cast<uint4*>(Bs + row * 64 + ((c ^ (row & 7)) << 3)) = vbv;
        }
        __syncthreads();
#pragma unroll
        for (int kk = 0; kk < 2; kk++) {
            bf16x8 a[4], b[4];
#pragma unroll
            for (int mi = 0; mi < 4; mi++) {
                int row = wr * 64 + mi * 16 + (lane & 15);
                a[mi] = *reinterpret_cast<const bf16x8*>(As + row * 64 + (((kk * 4 + (lane >> 4)) ^ (row & 7)) << 3));
            }
#pragma unroll
            for (int ni = 0; ni < 4; ni++) {
                int row = wc * 64 + ni * 16 + (lane & 15);
                b[ni] = *reinterpret_cast<const bf16x8*>(Bs + row * 64 + (((kk * 4 + (lane >> 4)) ^ (row & 7)) << 3));
            }
#pragma unroll
            for (int mi = 0; mi < 4; mi++)
#pragma unroll
                for (int ni = 0; ni < 4; ni++)
                    acc[mi][ni] = __builtin_amdgcn_mfma_f32_16x16x32_bf16(a[mi], b[ni], acc[mi][ni], 0, 0, 0);
        }
    }

    const int region = blockIdx.x >> 3;  // 0=q, 1=k, 2=v
    const float* bias = region == 0 ? bq : (region == 1 ? bk : bv);
    unsigned short* dst = region == 0 ? qb : (region == 1 ? kb : vb);
#pragma unroll
    for (int mi = 0; mi < 4; mi++) {
#pragma unroll
        for (int ni = 0; ni < 4; ni++) {
            int colg = cb + wc * 64 + ni * 16 + (lane & 15);
            int jj = colg & 1023;
            int hh = jj >> 6, d = jj & 63;
            float bval = bias[jj];
#pragma unroll
            for (int r = 0; r < 4; r++) {
                int n = rb + wr * 64 + mi * 16 + ((lane >> 4) << 2) + r;
                dst[((size_t)hh * N_TOK + n) * 64 + d] = f2bf(acc[mi][ni][r] + bval);
            }
        }
    }
}

// ---------------- K1b: transpose v [h][n][d] -> vbt [h][d][n] ----------------
__global__ void transpose_v(const unsigned short* __restrict__ vb, unsigned short* __restrict__ vbt) {
    int t = blockIdx.x * blockDim.x + threadIdx.x;
    int nc = t & 255, d = (t >> 8) & 63, h = t >> 14;
    int n0 = nc * 8;
    unsigned short tmp[8];
#pragma unroll
    for (int j = 0; j < 8; j++)
        tmp[j] = vb[((size_t)h * N_TOK + n0 + j) * 64 + d];
    *reinterpret_cast<uint4*>(vbt + ((size_t)h * 64 + d) * N_TOK + n0) = *reinterpret_cast<uint4*>(tmp);
}

// ---------------- K2a: per-chunk online-softmax stats (swapped-operand layout) ----------------
// grid (chunk=4, rowblock=32, head=16); 64 rows x 512 cols per block; dbuf K staging.
__launch_bounds__(256)
__global__ void attn_stats(const unsigned short* __restrict__ qb,
                           const unsigned short* __restrict__ kb,
                           const float* __restrict__ hist,
                           const float* __restrict__ beta_p,
                           float* __restrict__ m_part,
                           float* __restrict__ l_part) {
    __shared__ unsigned short Ks[2][64 * 64];
    const int tid = threadIdx.x;
    const int lane = tid & 63;
    const int g = lane >> 4;
    const int q15 = lane & 15;
    const int w = tid >> 6;
    const int chunk = blockIdx.x;
    const int rb = blockIdx.y;
    const int h = blockIdx.z;
    const int n0 = rb * 64;
    const int c_base = chunk * 512;
    const float beta = beta_p[0];
    const float scale = 0.125f;
    const int qrow = w * 16 + q15;

    // Q fragment: direct global load (B-operand rows = q-rows of this wave)
    const unsigned short* qsrc = qb + ((size_t)h * N_TOK + n0 + qrow) * 64;
    bf16x8 aq0 = *reinterpret_cast<const bf16x8*>(qsrc + 8 * g);
    bf16x8 aq1 = *reinterpret_cast<const bf16x8*>(qsrc + 8 * g + 32);

    // staging jobs: 2 per thread (rows jr and jr+32 of the 64x64 K tile)
    const int jr = tid >> 3, jc = tid & 7;

    float m = -1e30f, l = 0.0f;
    const float* hbase = hist + ((size_t)h * N_TOK + n0 + qrow) * N_TOK + c_base + 4 * g;

    // prologue: stage tile 0
    {
        uint4 k0 = *reinterpret_cast<const uint4*>(kb + ((size_t)h * N_TOK + c_base + jr) * 64 + jc * 8);
        uint4 k1 = *reinterpret_cast<const uint4*>(kb + ((size_t)h * N_TOK + c_base + jr + 32) * 64 + jc * 8);
        *reinterpret_cast<uint4*>(Ks[0] + jr * 64 + ((jc ^ (jr & 7)) << 3)) = k0;
        *reinterpret_cast<uint4*>(Ks[0] + (jr + 32) * 64 + ((jc ^ ((jr + 32) & 7)) << 3)) = k1;
    }
    __syncthreads();
    int cur = 0;

    for (int t = 0; t < 8; t++) {
        uint4 k0, k1;
        if (t < 7) {
            k0 = *reinterpret_cast<const uint4*>(kb + ((size_t)h * N_TOK + c_base + (t + 1) * 64 + jr) * 64 + jc * 8);
            k1 = *reinterpret_cast<const uint4*>(kb + ((size_t)h * N_TOK + c_base + (t + 1) * 64 + jr + 32) * 64 + jc * 8);
        }
        // hist loads (early issue)
        f32x4 h4[4];
#pragma unroll
        for (int nt = 0; nt < 4; nt++)
            h4[nt] = *reinterpret_cast<const f32x4*>(hbase + t * 64 + nt * 16);

        f32x4 s_acc[4];
#pragma unroll
        for (int nt = 0; nt < 4; nt++) {
            s_acc[nt] = zero4();
            int krow = nt * 16 + q15;
            bf16x8 kf0 = *reinterpret_cast<const bf16x8*>(Ks[cur] + krow * 64 + (((0 * 4 + g) ^ (q15 & 7)) << 3));
            bf16x8 kf1 = *reinterpret_cast<const bf16x8*>(Ks[cur] + krow * 64 + (((1 * 4 + g) ^ (q15 & 7)) << 3));
            s_acc[nt] = __builtin_amdgcn_mfma_f32_16x16x32_bf16(kf0, aq0, s_acc[nt], 0, 0, 0);
            s_acc[nt] = __builtin_amdgcn_mfma_f32_16x16x32_bf16(kf1, aq1, s_acc[nt], 0, 0, 0);
        }
        float sc[4][4];
#pragma unroll
        for (int nt = 0; nt < 4; nt++)
#pragma unroll
            for (int r = 0; r < 4; r++)
                sc[nt][r] = s_acc[nt][r] * scale + beta * h4[nt][r];

        float tm = sc[0][0];
#pragma unroll
        for (int nt = 0; nt < 4; nt++)
#pragma unroll
            for (int r = 0; r < 4; r++) tm = fmaxf(tm, sc[nt][r]);
        tm = fmaxf(tm, __shfl_xor(tm, 16));
        tm = fmaxf(tm, __shfl_xor(tm, 32));
        float mn = fmaxf(m, tm);
        float ps = 0.0f;
#pragma unroll
        for (int nt = 0; nt < 4; nt++)
#pragma unroll
            for (int r = 0; r < 4; r++) ps += __expf(sc[nt][r] - mn);
        ps += __shfl_xor(ps, 16);
        ps += __shfl_xor(ps, 32);
        l = l * __expf(m - mn) + ps;
        m = mn;

        if (t < 7) {
            *reinterpret_cast<uint4*>(Ks[cur ^ 1] + jr * 64 + ((jc ^ (jr & 7)) << 3)) = k0;
            *reinterpret_cast<uint4*>(Ks[cur ^ 1] + (jr + 32) * 64 + ((jc ^ ((jr + 32) & 7)) << 3)) = k1;
        }
        __syncthreads();
        cur ^= 1;
    }

    // partials layout: [h][rb][chunk][64 rows]; lanes g==0 write
    if (lane < 16) {
        const int base = ((h * 32 + rb) * 4 + chunk) * 64;
        m_part[base + w * 16 + lane] = m;
        l_part[base + w * 16 + lane] = l;
    }
}

// ---------------- K2b: finalize — merge stats, write attn/nh (float4), PV ----------------
// grid (chunk=4, rowblock=32, head=16); LDS 40KB: K dbuf 16K + V dbuf 16K + P 8K.
__launch_bounds__(256)
__global__ void attn_finalize(const unsigned short* __restrict__ qb,
                              const unsigned short* __restrict__ kb,
                              const unsigned short* __restrict__ vbt,
                              const float* __restrict__ hist,
                              const float* __restrict__ beta_p,
                              const float* __restrict__ m_part,
                              const float* __restrict__ l_part,
                              float* __restrict__ attn_out,
                              float* __restrict__ nh_out,
                              float* __restrict__ opart) {
    __shared__ unsigned short Ks[2][64 * 64];
    __shared__ unsigned short Vs[2][64 * 64];
    __shared__ unsigned short Ps[4][16 * 64];
    const int tid = threadIdx.x;
    const int lane = tid & 63;
    const int g = lane >> 4;
    const int q15 = lane & 15;
    const int w = tid >> 6;
    const int chunk = blockIdx.x;
    const int rb = blockIdx.y;
    const int h = blockIdx.z;
    const int n0 = rb * 64;
    const int c_base = chunk * 512;
    const float beta = beta_p[0];
    const float scale = 0.125f;
    const int qrow = w * 16 + q15;

    // Q fragment direct from global
    const unsigned short* qsrc = qb + ((size_t)h * N_TOK + n0 + qrow) * 64;
    bf16x8 aq0 = *reinterpret_cast<const bf16x8*>(qsrc + 8 * g);
    bf16x8 aq1 = *reinterpret_cast<const bf16x8*>(qsrc + 8 * g + 32);

    // merge per-chunk stats -> per-lane scalar m, inv_l for row qrow
    float m_row, inv_l;
    {
        const int pbase = (h * 32 + rb) * 4 * 64;
        float m0 = m_part[pbase + 0 * 64 + qrow];
        float m1 = m_part[pbase + 1 * 64 + qrow];
        float m2 = m_part[pbase + 2 * 64 + qrow];
        float m3 = m_part[pbase + 3 * 64 + qrow];
        float mm = fmaxf(fmaxf(m0, m1), fmaxf(m2, m3));
        float ll = l_part[pbase + 0 * 64 + qrow] * __expf(m0 - mm)
                 + l_part[pbase + 1 * 64 + qrow] * __expf(m1 - mm)
                 + l_part[pbase + 2 * 64 + qrow] * __expf(m2 - mm)
                 + l_part[pbase + 3 * 64 + qrow] * __expf(m3 - mm);
        m_row = mm;
        inv_l = 1.0f / ll;
    }

    f32x4 oacc[4];
#pragma unroll
    for (int di = 0; di < 4; di++) oacc[di] = zero4();

    const int jr = tid >> 3, jc = tid & 7;
    unsigned short* Psw = Ps[w];
    const float* hbase = hist + ((size_t)h * N_TOK + n0 + qrow) * N_TOK + c_base + 4 * g;
    float* abase = attn_out + ((size_t)h * N_TOK + n0 + qrow) * N_TOK + c_base + 4 * g;
    float* nbase = nh_out + ((size_t)h * N_TOK + n0 + qrow) * N_TOK + c_base + 4 * g;

    // prologue: stage tile 0 (K rows jr/jr+32; V d-rows jr/jr+32)
    {
        uint4 k0 = *reinterpret_cast<const uint4*>(kb + ((size_t)h * N_TOK + c_base + jr) * 64 + jc * 8);
        uint4 k1 = *reinterpret_cast<const uint4*>(kb + ((size_t)h * N_TOK + c_base + jr + 32) * 64 + jc * 8);
        uint4 v0 = *reinterpret_cast<const uint4*>(vbt + ((size_t)h * 64 + jr) * N_TOK + c_base + jc * 8);
        uint4 v1 = *reinterpret_cast<const uint4*>(vbt + ((size_t)h * 64 + jr + 32) * N_TOK + c_base + jc * 8);
        *reinterpret_cast<uint4*>(Ks[0] + jr * 64 + ((jc ^ (jr & 7)) << 3)) = k0;
        *reinterpret_cast<uint4*>(Ks[0] + (jr + 32) * 64 + ((jc ^ ((jr + 32) & 7)) << 3)) = k1;
        *reinterpret_cast<uint4*>(Vs[0] + jr * 64 + ((jc ^ (jr & 7)) << 3)) = v0;
        *reinterpret_cast<uint4*>(Vs[0] + (jr + 32) * 64 + ((jc ^ ((jr + 32) & 7)) << 3)) = v1;
    }
    __syncthreads();
    int cur = 0;

    for (int t = 0; t < 8; t++) {
        uint4 k0, k1, v0, v1;
        if (t < 7) {
            const int c1 = c_base + (t + 1) * 64;
            k0 = *reinterpret_cast<const uint4*>(kb + ((size_t)h * N_TOK + c1 + jr) * 64 + jc * 8);
            k1 = *reinterpret_cast<const uint4*>(kb + ((size_t)h * N_TOK + c1 + jr + 32) * 64 + jc * 8);
            v0 = *reinterpret_cast<const uint4*>(vbt + ((size_t)h * 64 + jr) * N_TOK + c1 + jc * 8);
            v1 = *reinterpret_cast<const uint4*>(vbt + ((size_t)h * 64 + jr + 32) * N_TOK + c1 + jc * 8);
        }
        f32x4 h4[4];
#pragma unroll
        for (int nt = 0; nt < 4; nt++)
            h4[nt] = *reinterpret_cast<const f32x4*>(hbase + t * 64 + nt * 16);

        // S = K · Q^T  (swapped operands: lane holds 4 consecutive k-cols of row qrow)
        f32x4 s_acc[4];
#pragma unroll
        for (int nt = 0; nt < 4; nt++) {
            s_acc[nt] = zero4();
            int krow = nt * 16 + q15;
            bf16x8 kf0 = *reinterpret_cast<const bf16x8*>(Ks[cur] + krow * 64 + (((0 * 4 + g) ^ (q15 & 7)) << 3));
            bf16x8 kf1 = *reinterpret_cast<const bf16x8*>(Ks[cur] + krow * 64 + (((1 * 4 + g) ^ (q15 & 7)) << 3));
            s_acc[nt] = __builtin_amdgcn_mfma_f32_16x16x32_bf16(kf0, aq0, s_acc[nt], 0, 0, 0);
            s_acc[nt] = __builtin_amdgcn_mfma_f32_16x16x32_bf16(kf1, aq1, s_acc[nt], 0, 0, 0);
        }

        // elementwise: attn/nh float4 stores + P pack into per-wave LDS
#pragma unroll
        for (int nt = 0; nt < 4; nt++) {
            float a0 = __expf(s_acc[nt][0] * scale + beta * h4[nt][0] - m_row) * inv_l;
            float a1 = __expf(s_acc[nt][1] * scale + beta * h4[nt][1] - m_row) * inv_l;
            float a2 = __expf(s_acc[nt][2] * scale + beta * h4[nt][2] - m_row) * inv_l;
            float a3 = __expf(s_acc[nt][3] * scale + beta * h4[nt][3] - m_row) * inv_l;
            f32x4 av, nv;
            av[0] = a0; av[1] = a1; av[2] = a2; av[3] = a3;
            nv[0] = a0 + h4[nt][0]; nv[1] = a1 + h4[nt][1];
            nv[2] = a2 + h4[nt][2]; nv[3] = a3 + h4[nt][3];
            *reinterpret_cast<f32x4*>(abase + t * 64 + nt * 16) = av;
            *reinterpret_cast<f32x4*>(nbase + t * 64 + nt * 16) = nv;
            ushort4 p;
            p.x = f2bf(a0); p.y = f2bf(a1); p.z = f2bf(a2); p.w = f2bf(a3);
            // P[q15][m = nt*16 + 4g .. +3], 8B slots XOR-swizzled by (q15&14)
            *reinterpret_cast<ushort4*>(Psw + q15 * 64 + (((4 * nt + g) ^ (q15 & 14)) << 2)) = p;
        }

        // PV: A = P (rows=q'), B = V^T (rows=d); oacc layout == original (rows w*16+4g+r, col d)
#pragma unroll
        for (int kk2 = 0; kk2 < 2; kk2++) {
            bf16x8 pa = *reinterpret_cast<const bf16x8*>(Psw + q15 * 64 + (((8 * kk2 + 2 * g) ^ (q15 & 14)) << 2));
#pragma unroll
            for (int di = 0; di < 4; di++) {
                int vrow = di * 16 + q15;
                bf16x8 vf = *reinterpret_cast<const bf16x8*>(Vs[cur] + vrow * 64 + (((kk2 * 4 + g) ^ (q15 & 7)) << 3));
                oacc[di] = __builtin_amdgcn_mfma_f32_16x16x32_bf16(pa, vf, oacc[di], 0, 0, 0);
            }
        }

        if (t < 7) {
            *reinterpret_cast<uint4*>(Ks[cur ^ 1] + jr * 64 + ((jc ^ (jr & 7)) << 3)) = k0;
            *reinterpret_cast<uint4*>(Ks[cur ^ 1] + (jr + 32) * 64 + ((jc ^ ((jr + 32) & 7)) << 3)) = k1;
            *reinterpret_cast<uint4*>(Vs[cur ^ 1] + jr * 64 + ((jc ^ (jr & 7)) << 3)) = v0;
            *reinterpret_cast<uint4*>(Vs[cur ^ 1] + (jr + 32) * 64 + ((jc ^ ((jr + 32) & 7)) << 3)) = v1;
        }
        __syncthreads();
        cur ^= 1;
    }

    // PV partial for this chunk: opart[chunk][h][n][d]
#pragma unroll
    for (int di = 0; di < 4; di++) {
#pragma unroll
        for (int r = 0; r < 4; r++) {
            int rl = w * 16 + g * 4 + r;
            int d = di * 16 + q15;
            opart[((size_t)(chunk * NHEAD + h) * N_TOK + n0 + rl) * 64 + d] = oacc[di][r];
        }
    }
}

// ---------------- K2c: reduce PV partials ----------------
__global__ void reduce_hv(const float4* __restrict__ op, float4* __restrict__ hv) {
    size_t i = (size_t)blockIdx.x * blockDim.x + threadIdx.x;
    const size_t C = (size_t)NHEAD * N_TOK * DHEAD / 4;
    float4 a = op[i], b = op[i + C], c = op[i + 2 * C], d = op[i + 3 * C];
    float4 r;
    r.x = a.x + b.x + c.x + d.x;
    r.y = a.y + b.y + c.y + d.y;
    r.z = a.z + b.z + c.z + d.z;
    r.w = a.w + b.w + c.w + d.w;
    hv[i] = r;
}

// ---------------- K3: output projection ----------------
__launch_bounds__(256)
__global__ void out_proj(const float* __restrict__ hv, const float* __restrict__ Wo,
                         const float* __restrict__ bo, float* __restrict__ out) {
    __shared__ float wos[64][129];
    const int tid = threadIdx.x;
    const int dd = tid & 63;
    const int w = tid >> 6;
    const int n0 = blockIdx.x * 16;
    float acc[4] = {0.f, 0.f, 0.f, 0.f};
    for (int kc = 0; kc < 1024; kc += 128) {
        __syncthreads();
#pragma unroll
        for (int i = 0; i < 32; i++) {
            int e = tid + 256 * i;
            int r = e >> 7, j = e & 127;
            wos[r][j] = Wo[(size_t)r * 1024 + kc + j];
        }
        __syncthreads();
#pragma unroll 4
        for (int k = 0; k < 128; k++) {
            float wv = wos[dd][k];
            int jg = kc + k;
            const float* hb = hv + ((size_t)(jg >> 6) * N_TOK) * 64 + (jg & 63);
#pragma unroll
            for (int q = 0; q < 4; q++) {
                acc[q] += hb[(size_t)(n0 + w + 4 * q) * 64] * wv;
            }
        }
    }
#pragma unroll
    for (int q = 0; q < 4; q++)
        out[(size_t)(n0 + w + 4 * q) * 64 + dd] = acc[q] + bo[dd];
}

extern "C" void kernel_launch(void* const* d_in, const int* in_sizes, int n_in,
                              void* d_out, int out_size, void* d_ws, size_t ws_size,
                              hipStream_t stream) {
    const float* x    = (const float*)d_in[0];
    const float* hist = (const float*)d_in[1];
    const float* Wq_w = (const float*)d_in[2];
    const float* Wq_b = (const float*)d_in[3];
    const float* Wk_w = (const float*)d_in[4];
    const float* Wk_b = (const float*)d_in[5];
    const float* Wv_w = (const float*)d_in[6];
    const float* Wv_b = (const float*)d_in[7];
    const float* Wo_w = (const float*)d_in[8];
    const float* Wo_b = (const float*)d_in[9];
    const float* beta = (const float*)d_in[10];

    float* out = (float*)d_out;
    float* attn_out = out + 131072;
    float* nh_out = attn_out + (size_t)NHEAD * N_TOK * N_TOK;

    unsigned short* xb  = (unsigned short*)d_ws;                 // 2M shorts
    unsigned short* wb  = xb + (size_t)N_TOK * HIDDEN;           // 3M shorts
    unsigned short* qb  = wb + (size_t)3 * HIDDEN * HIDDEN;      // 2M
    unsigned short* kb  = qb + (size_t)N_TOK * HIDDEN;
    unsigned short* vb  = kb + (size_t)N_TOK * HIDDEN;
    unsigned short* vbt = vb + (size_t)N_TOK * HIDDEN;
    float* hvb    = (float*)(vbt + (size_t)N_TOK * HIDDEN);      // 2M f32
    float* m_part = hvb + (size_t)N_TOK * HIDDEN;                // 128K f32
    float* l_part = m_part + 16 * 32 * 4 * 64;                   // 128K f32
    float* opart  = l_part + 16 * 32 * 4 * 64;                   // 8M f32 (32MB)

    cvt_kernel<<<2048, 256, 0, stream>>>(x, xb, N_TOK * HIDDEN / 4);
    cvt_kernel<<<1024, 256, 0, stream>>>(Wq_w, wb, HIDDEN * HIDDEN / 4);
    cvt_kernel<<<1024, 256, 0, stream>>>(Wk_w, wb + HIDDEN * HIDDEN, HIDDEN * HIDDEN / 4);
    cvt_kernel<<<1024, 256, 0, stream>>>(Wv_w, wb + 2 * HIDDEN * HIDDEN, HIDDEN * HIDDEN / 4);
    gemm_qkv<<<dim3(24, 16), 256, 0, stream>>>(xb, wb, Wq_b, Wk_b, Wv_b, qb, kb, vb);
    transpose_v<<<1024, 256, 0, stream>>>(vb, vbt);
    attn_stats<<<dim3(4, 32, 16), 256, 0, stream>>>(qb, kb, hist, beta, m_part, l_part);
    attn_finalize<<<dim3(4, 32, 16), 256, 0, stream>>>(qb, kb, vbt, hist, beta, m_part, l_part,
                                                       attn_out, nh_out, opart);
    reduce_hv<<<2048, 256, 0, stream>>>((const float4*)opart, (float4*)hvb);
    out_proj<<<128, 256, 0, stream>>>(hvb, Wo_w, Wo_b, out);
}

// Round 4
// 461.520 us; speedup vs baseline: 1.8118x; 1.0134x over previous
//
#include <hip/hip_runtime.h>
#include <hip/hip_bf16.h>

#define N_TOK 2048
#define HIDDEN 1024
#define NHEAD 16
#define DHEAD 64

typedef __attribute__((ext_vector_type(8))) short bf16x8;
typedef __attribute__((ext_vector_type(4))) float f32x4;

__device__ inline unsigned short f2bf(float x) {
    __hip_bfloat16 h = __float2bfloat16(x);
    return *reinterpret_cast<unsigned short*>(&h);
}

__device__ inline f32x4 zero4() {
    f32x4 z;
    z[0] = 0.f; z[1] = 0.f; z[2] = 0.f; z[3] = 0.f;
    return z;
}

// ---------------- K0: fused f32 -> bf16 conversion for x, Wq, Wk, Wv ----------------
// dst layout: [x (2M) | Wq (1M) | Wk (1M) | Wv (1M)] shorts, contiguous.
__global__ void cvt4_kernel(const float* __restrict__ x, const float* __restrict__ wq,
                            const float* __restrict__ wk, const float* __restrict__ wv,
                            unsigned short* __restrict__ dst) {
    int i = blockIdx.x * blockDim.x + threadIdx.x;  // 1310720 float4 jobs
    const float* src;
    int off;
    if (i < 524288)       { src = x;  off = i; }
    else if (i < 786432)  { src = wq; off = i - 524288; }
    else if (i < 1048576) { src = wk; off = i - 786432; }
    else                  { src = wv; off = i - 1048576; }
    float4 v = reinterpret_cast<const float4*>(src)[off];
    ushort4 o;
    o.x = f2bf(v.x); o.y = f2bf(v.y); o.z = f2bf(v.z); o.w = f2bf(v.w);
    reinterpret_cast<ushort4*>(dst)[i] = o;
}

// ---------------- K1: fused QKV GEMM (double-buffered, reg-prefetch) ----------------
__launch_bounds__(256)
__global__ void gemm_qkv(const unsigned short* __restrict__ xb,
                         const unsigned short* __restrict__ wb,
                         const float* __restrict__ bq, const float* __restrict__ bk,
                         const float* __restrict__ bv,
                         unsigned short* __restrict__ qb, unsigned short* __restrict__ kb,
                         unsigned short* __restrict__ vb) {
    __shared__ unsigned short As[2][128 * 64];
    __shared__ unsigned short Bs[2][128 * 64];
    const int tid = threadIdx.x;
    const int lane = tid & 63;
    const int w = tid >> 6;
    const int wr = w >> 1, wc = w & 1;
    const int rb = blockIdx.y * 128;
    const int cb = blockIdx.x * 128;
    const int r0 = tid >> 3, c0 = tid & 7;  // 4 jobs: rows r0+32i, col-chunk c0

    f32x4 acc[4][4];
    for (int i = 0; i < 4; i++)
        for (int j = 0; j < 4; j++) acc[i][j] = zero4();

    uint4 va[4], vb4[4];
    // prologue: load + stage tile 0
#pragma unroll
    for (int i = 0; i < 4; i++) {
        va[i]  = *reinterpret_cast<const uint4*>(xb + (size_t)(rb + r0 + 32 * i) * HIDDEN + c0 * 8);
        vb4[i] = *reinterpret_cast<const uint4*>(wb + (size_t)(cb + r0 + 32 * i) * HIDDEN + c0 * 8);
    }
#pragma unroll
    for (int i = 0; i < 4; i++) {
        int row = r0 + 32 * i;
        *reinterpret_cast<uint4*>(As[0] + row * 64 + ((c0 ^ (row & 7)) << 3)) = va[i];
        *reinterpret_cast<uint4*>(Bs[0] + row * 64 + ((c0 ^ (row & 7)) << 3)) = vb4[i];
    }
    __syncthreads();
    int cur = 0;

    for (int kt = 0; kt < 16; ++kt) {
        if (kt < 15) {
#pragma unroll
            for (int i = 0; i < 4; i++) {
                va[i]  = *reinterpret_cast<const uint4*>(xb + (size_t)(rb + r0 + 32 * i) * HIDDEN + (kt + 1) * 64 + c0 * 8);
                vb4[i] = *reinterpret_cast<const uint4*>(wb + (size_t)(cb + r0 + 32 * i) * HIDDEN + (kt + 1) * 64 + c0 * 8);
            }
        }
#pragma unroll
        for (int kk = 0; kk < 2; kk++) {
            bf16x8 a[4], b[4];
#pragma unroll
            for (int mi = 0; mi < 4; mi++) {
                int row = wr * 64 + mi * 16 + (lane & 15);
                a[mi] = *reinterpret_cast<const bf16x8*>(As[cur] + row * 64 + (((kk * 4 + (lane >> 4)) ^ (row & 7)) << 3));
            }
#pragma unroll
            for (int ni = 0; ni < 4; ni++) {
                int row = wc * 64 + ni * 16 + (lane & 15);
                b[ni] = *reinterpret_cast<const bf16x8*>(Bs[cur] + row * 64 + (((kk * 4 + (lane >> 4)) ^ (row & 7)) << 3));
            }
#pragma unroll
            for (int mi = 0; mi < 4; mi++)
#pragma unroll
                for (int ni = 0; ni < 4; ni++)
                    acc[mi][ni] = __builtin_amdgcn_mfma_f32_16x16x32_bf16(a[mi], b[ni], acc[mi][ni], 0, 0, 0);
        }
        if (kt < 15) {
#pragma unroll
            for (int i = 0; i < 4; i++) {
                int row = r0 + 32 * i;
                *reinterpret_cast<uint4*>(As[cur ^ 1] + row * 64 + ((c0 ^ (row & 7)) << 3)) = va[i];
                *reinterpret_cast<uint4*>(Bs[cur ^ 1] + row * 64 + ((c0 ^ (row & 7)) << 3)) = vb4[i];
            }
        }
        __syncthreads();
        cur ^= 1;
    }

    const int region = blockIdx.x >> 3;  // 0=q, 1=k, 2=v
    const float* bias = region == 0 ? bq : (region == 1 ? bk : bv);
    unsigned short* dst = region == 0 ? qb : (region == 1 ? kb : vb);
#pragma unroll
    for (int mi = 0; mi < 4; mi++) {
#pragma unroll
        for (int ni = 0; ni < 4; ni++) {
            int colg = cb + wc * 64 + ni * 16 + (lane & 15);
            int jj = colg & 1023;
            int hh = jj >> 6, d = jj & 63;
            float bval = bias[jj];
#pragma unroll
            for (int r = 0; r < 4; r++) {
                int n = rb + wr * 64 + mi * 16 + ((lane >> 4) << 2) + r;
                dst[((size_t)hh * N_TOK + n) * 64 + d] = f2bf(acc[mi][ni][r] + bval);
            }
        }
    }
}

// ---------------- K1b: transpose v [h][n][d] -> vbt [h][d][n] ----------------
__global__ void transpose_v(const unsigned short* __restrict__ vb, unsigned short* __restrict__ vbt) {
    int t = blockIdx.x * blockDim.x + threadIdx.x;
    int nc = t & 255, d = (t >> 8) & 63, h = t >> 14;
    int n0 = nc * 8;
    unsigned short tmp[8];
#pragma unroll
    for (int j = 0; j < 8; j++)
        tmp[j] = vb[((size_t)h * N_TOK + n0 + j) * 64 + d];
    *reinterpret_cast<uint4*>(vbt + ((size_t)h * 64 + d) * N_TOK + n0) = *reinterpret_cast<uint4*>(tmp);
}

// ---------------- K2a: per-chunk online-softmax stats (prefetch-pipelined) ----------------
__launch_bounds__(256)
__global__ void attn_stats(const unsigned short* __restrict__ qb,
                           const unsigned short* __restrict__ kb,
                           const float* __restrict__ hist,
                           const float* __restrict__ beta_p,
                           float* __restrict__ m_part,
                           float* __restrict__ l_part) {
    __shared__ unsigned short Ks[2][64 * 64];
    const int tid = threadIdx.x;
    const int lane = tid & 63;
    const int g = lane >> 4;
    const int q15 = lane & 15;
    const int w = tid >> 6;
    const int chunk = blockIdx.x;
    const int rb = blockIdx.y;
    const int h = blockIdx.z;
    const int n0 = rb * 64;
    const int c_base = chunk * 512;
    const float beta = beta_p[0];
    const float scale = 0.125f;
    const int qrow = w * 16 + q15;

    const unsigned short* qsrc = qb + ((size_t)h * N_TOK + n0 + qrow) * 64;
    bf16x8 aq0 = *reinterpret_cast<const bf16x8*>(qsrc + 8 * g);
    bf16x8 aq1 = *reinterpret_cast<const bf16x8*>(qsrc + 8 * g + 32);

    const int jr = tid >> 3, jc = tid & 7;

    float m = -1e30f, l = 0.0f;
    const float* hbase = hist + ((size_t)h * N_TOK + n0 + qrow) * N_TOK + c_base + 4 * g;

    f32x4 h4[4], h4n[4];
    // prologue: stage K tile 0, load hist tile 0
    {
        uint4 k0 = *reinterpret_cast<const uint4*>(kb + ((size_t)h * N_TOK + c_base + jr) * 64 + jc * 8);
        uint4 k1 = *reinterpret_cast<const uint4*>(kb + ((size_t)h * N_TOK + c_base + jr + 32) * 64 + jc * 8);
#pragma unroll
        for (int nt = 0; nt < 4; nt++) h4[nt] = *reinterpret_cast<const f32x4*>(hbase + nt * 16);
        *reinterpret_cast<uint4*>(Ks[0] + jr * 64 + ((jc ^ (jr & 7)) << 3)) = k0;
        *reinterpret_cast<uint4*>(Ks[0] + (jr + 32) * 64 + ((jc ^ ((jr + 32) & 7)) << 3)) = k1;
    }
    __syncthreads();
    int cur = 0;

    for (int t = 0; t < 8; t++) {
        uint4 k0, k1;
        if (t < 7) {
            k0 = *reinterpret_cast<const uint4*>(kb + ((size_t)h * N_TOK + c_base + (t + 1) * 64 + jr) * 64 + jc * 8);
            k1 = *reinterpret_cast<const uint4*>(kb + ((size_t)h * N_TOK + c_base + (t + 1) * 64 + jr + 32) * 64 + jc * 8);
#pragma unroll
            for (int nt = 0; nt < 4; nt++)
                h4n[nt] = *reinterpret_cast<const f32x4*>(hbase + (t + 1) * 64 + nt * 16);
        }

        f32x4 s_acc[4];
#pragma unroll
        for (int nt = 0; nt < 4; nt++) {
            s_acc[nt] = zero4();
            int krow = nt * 16 + q15;
            bf16x8 kf0 = *reinterpret_cast<const bf16x8*>(Ks[cur] + krow * 64 + ((g ^ (q15 & 7)) << 3));
            bf16x8 kf1 = *reinterpret_cast<const bf16x8*>(Ks[cur] + krow * 64 + (((4 + g) ^ (q15 & 7)) << 3));
            s_acc[nt] = __builtin_amdgcn_mfma_f32_16x16x32_bf16(kf0, aq0, s_acc[nt], 0, 0, 0);
            s_acc[nt] = __builtin_amdgcn_mfma_f32_16x16x32_bf16(kf1, aq1, s_acc[nt], 0, 0, 0);
        }
        float sc[4][4];
#pragma unroll
        for (int nt = 0; nt < 4; nt++)
#pragma unroll
            for (int r = 0; r < 4; r++)
                sc[nt][r] = s_acc[nt][r] * scale + beta * h4[nt][r];

        float tm = sc[0][0];
#pragma unroll
        for (int nt = 0; nt < 4; nt++)
#pragma unroll
            for (int r = 0; r < 4; r++) tm = fmaxf(tm, sc[nt][r]);
        tm = fmaxf(tm, __shfl_xor(tm, 16));
        tm = fmaxf(tm, __shfl_xor(tm, 32));
        float mn = fmaxf(m, tm);
        float ps = 0.0f;
#pragma unroll
        for (int nt = 0; nt < 4; nt++)
#pragma unroll
            for (int r = 0; r < 4; r++) ps += __expf(sc[nt][r] - mn);
        ps += __shfl_xor(ps, 16);
        ps += __shfl_xor(ps, 32);
        l = l * __expf(m - mn) + ps;
        m = mn;

        if (t < 7) {
            *reinterpret_cast<uint4*>(Ks[cur ^ 1] + jr * 64 + ((jc ^ (jr & 7)) << 3)) = k0;
            *reinterpret_cast<uint4*>(Ks[cur ^ 1] + (jr + 32) * 64 + ((jc ^ ((jr + 32) & 7)) << 3)) = k1;
#pragma unroll
            for (int nt = 0; nt < 4; nt++) h4[nt] = h4n[nt];
        }
        __syncthreads();
        cur ^= 1;
    }

    if (lane < 16) {
        const int base = ((h * 32 + rb) * 4 + chunk) * 64;
        m_part[base + w * 16 + lane] = m;
        l_part[base + w * 16 + lane] = l;
    }
}

// ---------------- K2b: finalize (prefetch-pipelined) ----------------
__launch_bounds__(256)
__global__ void attn_finalize(const unsigned short* __restrict__ qb,
                              const unsigned short* __restrict__ kb,
                              const unsigned short* __restrict__ vbt,
                              const float* __restrict__ hist,
                              const float* __restrict__ beta_p,
                              const float* __restrict__ m_part,
                              const float* __restrict__ l_part,
                              float* __restrict__ attn_out,
                              float* __restrict__ nh_out,
                              float* __restrict__ opart) {
    __shared__ unsigned short Ks[2][64 * 64];
    __shared__ unsigned short Vs[2][64 * 64];
    __shared__ unsigned short Ps[4][16 * 64];
    const int tid = threadIdx.x;
    const int lane = tid & 63;
    const int g = lane >> 4;
    const int q15 = lane & 15;
    const int w = tid >> 6;
    const int chunk = blockIdx.x;
    const int rb = blockIdx.y;
    const int h = blockIdx.z;
    const int n0 = rb * 64;
    const int c_base = chunk * 512;
    const float beta = beta_p[0];
    const float scale = 0.125f;
    const int qrow = w * 16 + q15;

    const unsigned short* qsrc = qb + ((size_t)h * N_TOK + n0 + qrow) * 64;
    bf16x8 aq0 = *reinterpret_cast<const bf16x8*>(qsrc + 8 * g);
    bf16x8 aq1 = *reinterpret_cast<const bf16x8*>(qsrc + 8 * g + 32);

    float m_row, inv_l;
    {
        const int pbase = (h * 32 + rb) * 4 * 64;
        float m0 = m_part[pbase + 0 * 64 + qrow];
        float m1 = m_part[pbase + 1 * 64 + qrow];
        float m2 = m_part[pbase + 2 * 64 + qrow];
        float m3 = m_part[pbase + 3 * 64 + qrow];
        float mm = fmaxf(fmaxf(m0, m1), fmaxf(m2, m3));
        float ll = l_part[pbase + 0 * 64 + qrow] * __expf(m0 - mm)
                 + l_part[pbase + 1 * 64 + qrow] * __expf(m1 - mm)
                 + l_part[pbase + 2 * 64 + qrow] * __expf(m2 - mm)
                 + l_part[pbase + 3 * 64 + qrow] * __expf(m3 - mm);
        m_row = mm;
        inv_l = 1.0f / ll;
    }

    f32x4 oacc[4];
#pragma unroll
    for (int di = 0; di < 4; di++) oacc[di] = zero4();

    const int jr = tid >> 3, jc = tid & 7;
    unsigned short* Psw = Ps[w];
    const float* hbase = hist + ((size_t)h * N_TOK + n0 + qrow) * N_TOK + c_base + 4 * g;
    float* abase = attn_out + ((size_t)h * N_TOK + n0 + qrow) * N_TOK + c_base + 4 * g;
    float* nbase = nh_out + ((size_t)h * N_TOK + n0 + qrow) * N_TOK + c_base + 4 * g;

    f32x4 h4[4], h4n[4];
    // prologue: stage K/V tile 0 + load hist tile 0
    {
        uint4 k0 = *reinterpret_cast<const uint4*>(kb + ((size_t)h * N_TOK + c_base + jr) * 64 + jc * 8);
        uint4 k1 = *reinterpret_cast<const uint4*>(kb + ((size_t)h * N_TOK + c_base + jr + 32) * 64 + jc * 8);
        uint4 v0 = *reinterpret_cast<const uint4*>(vbt + ((size_t)h * 64 + jr) * N_TOK + c_base + jc * 8);
        uint4 v1 = *reinterpret_cast<const uint4*>(vbt + ((size_t)h * 64 + jr + 32) * N_TOK + c_base + jc * 8);
#pragma unroll
        for (int nt = 0; nt < 4; nt++) h4[nt] = *reinterpret_cast<const f32x4*>(hbase + nt * 16);
        *reinterpret_cast<uint4*>(Ks[0] + jr * 64 + ((jc ^ (jr & 7)) << 3)) = k0;
        *reinterpret_cast<uint4*>(Ks[0] + (jr + 32) * 64 + ((jc ^ ((jr + 32) & 7)) << 3)) = k1;
        *reinterpret_cast<uint4*>(Vs[0] + jr * 64 + ((jc ^ (jr & 7)) << 3)) = v0;
        *reinterpret_cast<uint4*>(Vs[0] + (jr + 32) * 64 + ((jc ^ ((jr + 32) & 7)) << 3)) = v1;
    }
    __syncthreads();
    int cur = 0;

    for (int t = 0; t < 8; t++) {
        uint4 k0, k1, v0, v1;
        if (t < 7) {
            const int c1 = c_base + (t + 1) * 64;
            k0 = *reinterpret_cast<const uint4*>(kb + ((size_t)h * N_TOK + c1 + jr) * 64 + jc * 8);
            k1 = *reinterpret_cast<const uint4*>(kb + ((size_t)h * N_TOK + c1 + jr + 32) * 64 + jc * 8);
            v0 = *reinterpret_cast<const uint4*>(vbt + ((size_t)h * 64 + jr) * N_TOK + c1 + jc * 8);
            v1 = *reinterpret_cast<const uint4*>(vbt + ((size_t)h * 64 + jr + 32) * N_TOK + c1 + jc * 8);
#pragma unroll
            for (int nt = 0; nt < 4; nt++)
                h4n[nt] = *reinterpret_cast<const f32x4*>(hbase + (t + 1) * 64 + nt * 16);
        }

        f32x4 s_acc[4];
#pragma unroll
        for (int nt = 0; nt < 4; nt++) {
            s_acc[nt] = zero4();
            int krow = nt * 16 + q15;
            bf16x8 kf0 = *reinterpret_cast<const bf16x8*>(Ks[cur] + krow * 64 + ((g ^ (q15 & 7)) << 3));
            bf16x8 kf1 = *reinterpret_cast<const bf16x8*>(Ks[cur] + krow * 64 + (((4 + g) ^ (q15 & 7)) << 3));
            s_acc[nt] = __builtin_amdgcn_mfma_f32_16x16x32_bf16(kf0, aq0, s_acc[nt], 0, 0, 0);
            s_acc[nt] = __builtin_amdgcn_mfma_f32_16x16x32_bf16(kf1, aq1, s_acc[nt], 0, 0, 0);
        }

#pragma unroll
        for (int nt = 0; nt < 4; nt++) {
            float a0 = __expf(s_acc[nt][0] * scale + beta * h4[nt][0] - m_row) * inv_l;
            float a1 = __expf(s_acc[nt][1] * scale + beta * h4[nt][1] - m_row) * inv_l;
            float a2 = __expf(s_acc[nt][2] * scale + beta * h4[nt][2] - m_row) * inv_l;
            float a3 = __expf(s_acc[nt][3] * scale + beta * h4[nt][3] - m_row) * inv_l;
            f32x4 av, nv;
            av[0] = a0; av[1] = a1; av[2] = a2; av[3] = a3;
            nv[0] = a0 + h4[nt][0]; nv[1] = a1 + h4[nt][1];
            nv[2] = a2 + h4[nt][2]; nv[3] = a3 + h4[nt][3];
            *reinterpret_cast<f32x4*>(abase + t * 64 + nt * 16) = av;
            *reinterpret_cast<f32x4*>(nbase + t * 64 + nt * 16) = nv;
            ushort4 p;
            p.x = f2bf(a0); p.y = f2bf(a1); p.z = f2bf(a2); p.w = f2bf(a3);
            *reinterpret_cast<ushort4*>(Psw + q15 * 64 + (((4 * nt + g) ^ (q15 & 14)) << 2)) = p;
        }

#pragma unroll
        for (int kk2 = 0; kk2 < 2; kk2++) {
            bf16x8 pa = *reinterpret_cast<const bf16x8*>(Psw + q15 * 64 + (((8 * kk2 + 2 * g) ^ (q15 & 14)) << 2));
#pragma unroll
            for (int di = 0; di < 4; di++) {
                int vrow = di * 16 + q15;
                bf16x8 vf = *reinterpret_cast<const bf16x8*>(Vs[cur] + vrow * 64 + (((kk2 * 4 + g) ^ (q15 & 7)) << 3));
                oacc[di] = __builtin_amdgcn_mfma_f32_16x16x32_bf16(pa, vf, oacc[di], 0, 0, 0);
            }
        }

        if (t < 7) {
            *reinterpret_cast<uint4*>(Ks[cur ^ 1] + jr * 64 + ((jc ^ (jr & 7)) << 3)) = k0;
            *reinterpret_cast<uint4*>(Ks[cur ^ 1] + (jr + 32) * 64 + ((jc ^ ((jr + 32) & 7)) << 3)) = k1;
            *reinterpret_cast<uint4*>(Vs[cur ^ 1] + jr * 64 + ((jc ^ (jr & 7)) << 3)) = v0;
            *reinterpret_cast<uint4*>(Vs[cur ^ 1] + (jr + 32) * 64 + ((jc ^ ((jr + 32) & 7)) << 3)) = v1;
#pragma unroll
            for (int nt = 0; nt < 4; nt++) h4[nt] = h4n[nt];
        }
        __syncthreads();
        cur ^= 1;
    }

#pragma unroll
    for (int di = 0; di < 4; di++) {
#pragma unroll
        for (int r = 0; r < 4; r++) {
            int rl = w * 16 + g * 4 + r;
            int d = di * 16 + q15;
            opart[((size_t)(chunk * NHEAD + h) * N_TOK + n0 + rl) * 64 + d] = oacc[di][r];
        }
    }
}

// ---------------- K2c: reduce PV partials ----------------
__global__ void reduce_hv(const float4* __restrict__ op, float4* __restrict__ hv) {
    size_t i = (size_t)blockIdx.x * blockDim.x + threadIdx.x;
    const size_t C = (size_t)NHEAD * N_TOK * DHEAD / 4;
    float4 a = op[i], b = op[i + C], c = op[i + 2 * C], d = op[i + 3 * C];
    float4 r;
    r.x = a.x + b.x + c.x + d.x;
    r.y = a.y + b.y + c.y + d.y;
    r.z = a.z + b.z + c.z + d.z;
    r.w = a.w + b.w + c.w + d.w;
    hv[i] = r;
}

// ---------------- K3: output projection ----------------
__launch_bounds__(256)
__global__ void out_proj(const float* __restrict__ hv, const float* __restrict__ Wo,
                         const float* __restrict__ bo, float* __restrict__ out) {
    __shared__ float wos[64][129];
    const int tid = threadIdx.x;
    const int dd = tid & 63;
    const int w = tid >> 6;
    const int n0 = blockIdx.x * 16;
    float acc[4] = {0.f, 0.f, 0.f, 0.f};
    for (int kc = 0; kc < 1024; kc += 128) {
        __syncthreads();
#pragma unroll
        for (int i = 0; i < 32; i++) {
            int e = tid + 256 * i;
            int r = e >> 7, j = e & 127;
            wos[r][j] = Wo[(size_t)r * 1024 + kc + j];
        }
        __syncthreads();
#pragma unroll 4
        for (int k = 0; k < 128; k++) {
            float wv = wos[dd][k];
            int jg = kc + k;
            const float* hb = hv + ((size_t)(jg >> 6) * N_TOK) * 64 + (jg & 63);
#pragma unroll
            for (int q = 0; q < 4; q++) {
                acc[q] += hb[(size_t)(n0 + w + 4 * q) * 64] * wv;
            }
        }
    }
#pragma unroll
    for (int q = 0; q < 4; q++)
        out[(size_t)(n0 + w + 4 * q) * 64 + dd] = acc[q] + bo[dd];
}

extern "C" void kernel_launch(void* const* d_in, const int* in_sizes, int n_in,
                              void* d_out, int out_size, void* d_ws, size_t ws_size,
                              hipStream_t stream) {
    const float* x    = (const float*)d_in[0];
    const float* hist = (const float*)d_in[1];
    const float* Wq_w = (const float*)d_in[2];
    const float* Wq_b = (const float*)d_in[3];
    const float* Wk_w = (const float*)d_in[4];
    const float* Wk_b = (const float*)d_in[5];
    const float* Wv_w = (const float*)d_in[6];
    const float* Wv_b = (const float*)d_in[7];
    const float* Wo_w = (const float*)d_in[8];
    const float* Wo_b = (const float*)d_in[9];
    const float* beta = (const float*)d_in[10];

    float* out = (float*)d_out;
    float* attn_out = out + 131072;
    float* nh_out = attn_out + (size_t)NHEAD * N_TOK * N_TOK;

    unsigned short* xb  = (unsigned short*)d_ws;                 // 2M shorts
    unsigned short* wb  = xb + (size_t)N_TOK * HIDDEN;           // 3M shorts
    unsigned short* qb  = wb + (size_t)3 * HIDDEN * HIDDEN;      // 2M
    unsigned short* kb  = qb + (size_t)N_TOK * HIDDEN;
    unsigned short* vb  = kb + (size_t)N_TOK * HIDDEN;
    unsigned short* vbt = vb + (size_t)N_TOK * HIDDEN;
    float* hvb    = (float*)(vbt + (size_t)N_TOK * HIDDEN);      // 2M f32
    float* m_part = hvb + (size_t)N_TOK * HIDDEN;                // 128K f32
    float* l_part = m_part + 16 * 32 * 4 * 64;                   // 128K f32
    float* opart  = l_part + 16 * 32 * 4 * 64;                   // 8M f32 (32MB)

    cvt4_kernel<<<5120, 256, 0, stream>>>(x, Wq_w, Wk_w, Wv_w, xb);
    gemm_qkv<<<dim3(24, 16), 256, 0, stream>>>(xb, wb, Wq_b, Wk_b, Wv_b, qb, kb, vb);
    transpose_v<<<1024, 256, 0, stream>>>(vb, vbt);
    attn_stats<<<dim3(4, 32, 16), 256, 0, stream>>>(qb, kb, hist, beta, m_part, l_part);
    attn_finalize<<<dim3(4, 32, 16), 256, 0, stream>>>(qb, kb, vbt, hist, beta, m_part, l_part,
                                                       attn_out, nh_out, opart);
    reduce_hv<<<2048, 256, 0, stream>>>((const float4*)opart, (float4*)hvb);
    out_proj<<<128, 256, 0, stream>>>(hvb, Wo_w, Wo_b, out);
}